// Round 20
// baseline (94.762 us; speedup 1.0000x reference)
//
#include <hip/hip_runtime.h>

// Problem constants (fixed by setup_inputs in the reference)
#define B_  8
#define N_  3072
#define C_  256
#define H_  128
#define W_  96
#define HW_ (H_ * W_)
#define NC_ (B_ * HW_)          // 98304 cells (~78% EMPTY: 0.25 tokens/cell)
#define NT_ (B_ * N_)           // 24576 tokens
#define EPSF 1e-6f

// Gaussian 3x3, sigma=2 (normalized): center, edge, corner
#define KW0 0.13080118f
#define KW1 0.11543166f
#define KW2 0.10186807f

// fused-kernel tiling: block = (b, 2-row pair, 32-col x-tile, 128-ch group)
#define CG_ 128                 // channels per block (lane covers 2 via float2)
#define XT_ 32                  // x columns written per block
#define XS_ 34                  // staged columns (32 + 2 halo)
#define CPB 132                 // bf16 channel pad (row = 264 B; breaks pow2 banks)
#define RY_ 2                   // output rows per block (4 staged rows, 1 per wave)
#define PRE_ 12                 // single-shot token prefetch depth (~90% of windows)
#define NWG_ (B_ * (H_ / RY_) * 3 * 2)   // 3072 blocks; 3072 % 8 == 0

// ws layout (u32 units) — round-4-proven layout (ws is actually ~384 MB).
#define OFF_ASTART 0
#define OFF_ACUR   (NC_ + 1)
#define OFF_BSUM   (2 * NC_ + 1)
#define OFF_BOFF   (2 * NC_ + 1 + 384)
#define OFF_TOKS   (2 * NC_ + 1 + 768)

__device__ __forceinline__ unsigned f2bf(float f) {   // RNE f32->bf16 (low 16)
    const unsigned u = __float_as_uint(f);
    return (u + 0x7FFFu + ((u >> 16) & 1u)) >> 16;
}

// packed 2-wide f32 FMA (VOP3P): d = a*b + c per half
__device__ __forceinline__ float2 pk_fma(float2 a, float2 b, float2 c) {
    float2 d;
    asm("v_pk_fma_f32 %0, %1, %2, %3" : "=v"(d) : "v"(a), "v"(b), "v"(c));
    return d;
}

// bf16x2 word -> float2 {even_ch, odd_ch}
__device__ __forceinline__ float2 unpk(unsigned w) {
    return make_float2(__uint_as_float(w << 16),
                       __uint_as_float(w & 0xFFFF0000u));
}

__device__ __forceinline__ void token_cell(const float* __restrict__ loc, int token,
                                           int& b, int& ix, int& iy) {
    b = token / N_;
    const float lx = fminf(fmaxf(loc[2 * token + 0], -1.0f), 1.0f);
    const float ly = fminf(fmaxf(loc[2 * token + 1], -1.0f), 1.0f);
    const float px = 0.5f * (lx + 1.0f) * (float)W_ - 0.5f;
    const float py = 0.5f * (ly + 1.0f) * (float)H_ - 0.5f;
    ix = (int)rintf(px); ix = min(max(ix, 0), W_ - 1);   // rintf = round-half-even = jnp.round
    iy = (int)rintf(py); iy = min(max(iy, 0), H_ - 1);
}

// Pass 1: histogram tokens into cells
__global__ void count_k(const float* __restrict__ loc, unsigned* __restrict__ cnts) {
    const int token = blockIdx.x * 256 + threadIdx.x;   // NT_ threads
    int b, ix, iy;
    token_cell(loc, token, b, ix, iy);
    atomicAdd(&cnts[b * HW_ + iy * W_ + ix], 1u);
}

// Pass 2a: per-block (256-cell) sums
__global__ void scanA(const unsigned* __restrict__ cnts, unsigned* __restrict__ Bsum) {
    const int i = blockIdx.x * 256 + threadIdx.x;
    int c = (int)cnts[i];
    #pragma unroll
    for (int off = 32; off > 0; off >>= 1) c += __shfl_down(c, off, 64);
    __shared__ int s[4];
    if ((threadIdx.x & 63) == 0) s[threadIdx.x >> 6] = c;
    __syncthreads();
    if (threadIdx.x == 0) Bsum[blockIdx.x] = (unsigned)(s[0] + s[1] + s[2] + s[3]);
}

// Pass 2b: exclusive scan of the 384 block sums (single block)
__global__ void scanB(const unsigned* __restrict__ Bsum, unsigned* __restrict__ Boff) {
    __shared__ unsigned s[512];
    const int t = threadIdx.x;
    const unsigned v = (t < 384) ? Bsum[t] : 0u;
    s[t] = v;
    __syncthreads();
    #pragma unroll
    for (int off = 1; off < 512; off <<= 1) {
        const unsigned a = (t >= off) ? s[t - off] : 0u;
        __syncthreads();
        s[t] += a;
        __syncthreads();
    }
    if (t < 384) Boff[t] = s[t] - v;   // exclusive
}

// Pass 2c: per-block exclusive scan + block offset -> Astart (and cursor copy)
__global__ void scanC(const unsigned* __restrict__ Boff,
                      unsigned* __restrict__ Astart, unsigned* __restrict__ Acur) {
    __shared__ unsigned s[256];
    const int t = threadIdx.x;
    const int i = blockIdx.x * 256 + t;
    const unsigned v = Acur[i];        // counts currently live in Acur
    s[t] = v;
    __syncthreads();
    #pragma unroll
    for (int off = 1; off < 256; off <<= 1) {
        const unsigned a = (t >= off) ? s[t - off] : 0u;
        __syncthreads();
        s[t] += a;
        __syncthreads();
    }
    const unsigned excl = s[t] - v + Boff[blockIdx.x];
    Astart[i] = excl;
    Acur[i]   = excl;                  // cursor starts at bin start
    if (i == 0) Astart[NC_] = NT_;     // total
}

// Pass 3: scatter token ids (packed with x) into bins
__global__ void fill_bins(const float* __restrict__ loc,
                          unsigned* __restrict__ Acur, unsigned* __restrict__ toks) {
    const int token = blockIdx.x * 256 + threadIdx.x;
    int b, ix, iy;
    token_cell(loc, token, b, ix, iy);
    const unsigned pos = atomicAdd(&Acur[b * HW_ + iy * W_ + ix], 1u);
    toks[pos] = ((unsigned)ix << 20) | (unsigned)token;
}

// Pass 4 (FUSED, 2 rows/block, pk_fma fill, XCD-swizzled, early toks issue):
//   vs round-19 best: the whole 34-cell window's toks (up to 12) are loaded
//   in ONE batch issued BEFORE the LDS zero-init, hiding that dependent-load
//   round under the init + barrier; post-barrier the walk is a single xf
//   round for ~90% of windows (rare >12-token tails fall back to batch-4).
__global__ __launch_bounds__(256) void fused_k(const float* __restrict__ xf,
        const unsigned* __restrict__ Astart, const unsigned* __restrict__ toks,
        float* __restrict__ out) {
    // XCD-aware swizzle: each XCD's 384-block chunk covers exactly one b.
    const int blk = (blockIdx.x & 7) * (NWG_ / 8) + (blockIdx.x >> 3);
    const int cg = blk & 1;              // ((b*64 + yp)*3 + xt)*2 + cg
    const int t2 = blk >> 1;
    const int xt = t2 % 3;
    const int t3 = t2 / 3;
    const int yp = t3 & 63;
    const int b  = t3 >> 6;
    const int y0 = yp * RY_;
    const int xs = xt * XT_;
    const int lane = threadIdx.x & 63;
    const int wv = threadIdx.x >> 6;

    __shared__ __align__(16) unsigned short means[4 * XS_ * CPB];   // 35904 B
    __shared__ unsigned long long cmask[4];
    __shared__ float coef[RY_][XT_][10];                            // 2560 B

    // (1) per-wave Astart stage for row y0-1+wv. OOB rows -> cmask 0, empty.
    const int yg = y0 - 1 + wv;
    const bool inrow = ((unsigned)yg < (unsigned)H_);
    unsigned p0, p1;
    {
        unsigned a = 0u;
        if (inrow && lane < XS_ + 1) {
            int g = xs - 1 + lane;                 // [xs-1, xs+33]
            g = min(max(g, 0), W_);                // Astart[..+W_] = row end
            a = Astart[b * HW_ + yg * W_ + g];
        }
        const unsigned an = __shfl_down(a, 1, 64);
        const unsigned long long mask = __ballot(lane < XS_ && an > a);
        if (lane == 0) cmask[wv] = mask;
        p0 = __shfl(a, 0, 64);
        p1 = __shfl(a, XS_, 64);
    }

    // (1b) EARLY single-shot toks prefetch for the window (latency hides
    //      under the zero-init below; wave-uniform guards are cheap).
    unsigned vv[PRE_];
    #pragma unroll
    for (int j = 0; j < PRE_; ++j) {
        vv[j] = 0u;
        if (inrow && p0 + j < p1) vv[j] = toks[p0 + j];
    }

    // (2) zero-init means (bf16 +0.0 = 0x0000); empty cells stay exactly 0
    {
        uint4* p4 = (uint4*)means;
        for (int i = threadIdx.x; i < 4 * XS_ * CPB / 8; i += 256)
            p4[i] = make_uint4(0u, 0u, 0u, 0u);
    }
    __syncthreads();   // A: init + cmask ready

    // (3a) wave 0: per-cell coefficient table (64 cells = 2 rows x 32 x)
    if (wv == 0) {
        const int r  = lane >> 5;
        const int xl = lane & 31;
        const int xi = xl + 1;
        const unsigned long long cm0 = cmask[r], cm1 = cmask[r + 1],
                                 cm2 = cmask[r + 2];
        const float w0 = ((cm0 >> (xi - 1)) & 1ULL) ? KW2 : 0.0f;
        const float w1 = ((cm0 >> xi)       & 1ULL) ? KW1 : 0.0f;
        const float w2 = ((cm0 >> (xi + 1)) & 1ULL) ? KW2 : 0.0f;
        const float w3 = ((cm1 >> (xi - 1)) & 1ULL) ? KW1 : 0.0f;
        const float w5 = ((cm1 >> (xi + 1)) & 1ULL) ? KW1 : 0.0f;
        const float w6 = ((cm2 >> (xi - 1)) & 1ULL) ? KW2 : 0.0f;
        const float w7 = ((cm2 >> xi)       & 1ULL) ? KW1 : 0.0f;
        const float w8 = ((cm2 >> (xi + 1)) & 1ULL) ? KW2 : 0.0f;
        const bool ne  = (cm1 >> xi) & 1ULL;
        const float ms = ((w0 + w2) + (w6 + w8)) + ((w1 + w7) + (w3 + w5));
        const float inv = ne ? 0.0f : 1.0f / (ms + EPSF);   // ms==0 -> all 0
        coef[r][xl][0] = w0 * inv;
        coef[r][xl][1] = w1 * inv;
        coef[r][xl][2] = w2 * inv;
        coef[r][xl][3] = w3 * inv;
        coef[r][xl][4] = ne ? 1.0f : 0.0f;   // self (nonempty copy)
        coef[r][xl][5] = w5 * inv;
        coef[r][xl][6] = w6 * inv;
        coef[r][xl][7] = w7 * inv;
        coef[r][xl][8] = w8 * inv;
    }

    // (3b) all waves: one xf round for the prefetched window, then flush;
    //      rare tails (>PRE_ tokens) continue with the batch-4 loop.
    if (inrow && p0 < p1) {
        unsigned* msw = (unsigned*)(means + wv * XS_ * CPB);   // u32 view
        const unsigned nwin = min(p1 - p0, (unsigned)PRE_);

        float2 ff[PRE_];
        #pragma unroll
        for (int j = 0; j < PRE_; ++j)
            if (j < (int)nwin)
                ff[j] = *(const float2*)&xf[(size_t)(vv[j] & 0xFFFFFu) * C_
                                            + cg * CG_ + 2 * lane];

        int cur_xi = -1;
        float acc0 = 0.0f, acc1 = 0.0f;
        unsigned cnt = 0u;
        #pragma unroll
        for (int j = 0; j < PRE_; ++j) {
            if (j >= (int)nwin) break;
            const int xi = (int)(vv[j] >> 20) - xs + 1;   // in [0, 34)
            if (xi != cur_xi) {
                if (cur_xi >= 0) {
                    const float rcp = 1.0f / ((float)cnt + EPSF);
                    msw[cur_xi * (CPB / 2) + lane] =
                        f2bf(acc0 * rcp) | (f2bf(acc1 * rcp) << 16);
                }
                acc0 = acc1 = 0.0f; cnt = 0u; cur_xi = xi;
            }
            acc0 += ff[j].x; acc1 += ff[j].y; ++cnt;
        }
        // tail: windows with more than PRE_ tokens (rare)
        for (unsigned p = p0 + PRE_; p < p1; p += 4) {
            unsigned tv[4]; float2 tf[4];
            #pragma unroll
            for (int j = 0; j < 4; ++j)
                if (p + j < p1) tv[j] = toks[p + j];
            #pragma unroll
            for (int j = 0; j < 4; ++j)
                if (p + j < p1)
                    tf[j] = *(const float2*)&xf[(size_t)(tv[j] & 0xFFFFFu) * C_
                                                + cg * CG_ + 2 * lane];
            #pragma unroll
            for (int j = 0; j < 4; ++j) {
                if (p + j >= p1) break;
                const int xi = (int)(tv[j] >> 20) - xs + 1;
                if (xi != cur_xi) {
                    if (cur_xi >= 0) {
                        const float rcp = 1.0f / ((float)cnt + EPSF);
                        msw[cur_xi * (CPB / 2) + lane] =
                            f2bf(acc0 * rcp) | (f2bf(acc1 * rcp) << 16);
                    }
                    acc0 = acc1 = 0.0f; cnt = 0u; cur_xi = xi;
                }
                acc0 += tf[j].x; acc1 += tf[j].y; ++cnt;
            }
        }
        if (cur_xi >= 0) {
            const float rcp = 1.0f / ((float)cnt + EPSF);
            msw[cur_xi * (CPB / 2) + lane] = f2bf(acc0 * rcp) | (f2bf(acc1 * rcp) << 16);
        }
    }
    __syncthreads();   // B: means + coef ready

    // (4) fill: thread = fixed x (xl) x 16 channels x 2 rows; branchless
    //     9-term blend via uint2 LDS reads + pair-unpack + v_pk_fma_f32.
    const int xl  = threadIdx.x & 31;
    const int sub = threadIdx.x >> 5;
    const int xi  = xl + 1;
    const int c0  = sub * 16;

    #pragma unroll
    for (int r = 0; r < RY_; ++r) {
        float c9[9];
        #pragma unroll
        for (int j = 0; j < 9; ++j) c9[j] = coef[r][xl][j];

        float2 acc[8];
        #pragma unroll
        for (int p = 0; p < 8; ++p) acc[p] = make_float2(0.f, 0.f);

        #pragma unroll
        for (int j = 0; j < 9; ++j) {
            const int slot = r + j / 3;
            const int col  = xi - 1 + j % 3;
            const uint2* b2 = (const uint2*)(means + (slot * XS_ + col) * CPB + c0);
            const float2 wp = make_float2(c9[j], c9[j]);
            #pragma unroll
            for (int p = 0; p < 4; ++p) {
                const uint2 w = b2[p];          // channels c0+4p .. c0+4p+3
                acc[2 * p]     = pk_fma(unpk(w.x), wp, acc[2 * p]);
                acc[2 * p + 1] = pk_fma(unpk(w.y), wp, acc[2 * p + 1]);
            }
        }
        float* op = out + ((size_t)(b * C_ + cg * CG_ + c0)) * HW_
                        + (size_t)(y0 + r) * W_ + xs + xl;
        #pragma unroll
        for (int p = 0; p < 8; ++p) {
            op[(size_t)(2 * p)     * HW_] = acc[p].x;
            op[(size_t)(2 * p + 1) * HW_] = acc[p].y;
        }
    }
}

extern "C" void kernel_launch(void* const* d_in, const int* in_sizes, int n_in,
                              void* d_out, int out_size, void* d_ws, size_t ws_size,
                              hipStream_t stream) {
    const float* x   = (const float*)d_in[0];   // (B, N, C) f32
    const float* loc = (const float*)d_in[1];   // (B, N, 2) f32
    float* out = (float*)d_out;                 // (B, C, H, W) f32

    unsigned* W32 = (unsigned*)d_ws;
    unsigned* Astart = W32 + OFF_ASTART;
    unsigned* Acur   = W32 + OFF_ACUR;
    unsigned* Bsum   = W32 + OFF_BSUM;
    unsigned* Boff   = W32 + OFF_BOFF;
    unsigned* toks   = W32 + OFF_TOKS;

    hipMemsetAsync(Acur, 0, (size_t)NC_ * sizeof(unsigned), stream);

    count_k  <<<NT_ / 256, 256, 0, stream>>>(loc, Acur);
    scanA    <<<NC_ / 256, 256, 0, stream>>>(Acur, Bsum);
    scanB    <<<1, 512, 0, stream>>>(Bsum, Boff);
    scanC    <<<NC_ / 256, 256, 0, stream>>>(Boff, Astart, Acur);
    fill_bins<<<NT_ / 256, 256, 0, stream>>>(loc, Acur, toks);

    // grid = 3072 blocks (XCD-swizzled inside the kernel)
    fused_k<<<NWG_, 256, 0, stream>>>(x, Astart, toks, out);
}

// Round 21
// 56.699 us; speedup vs baseline: 1.6713x; 1.6713x over previous
//
#include <hip/hip_runtime.h>

// Problem constants (fixed by setup_inputs in the reference)
#define B_  8
#define N_  3072
#define C_  256
#define H_  128
#define W_  96
#define HW_ (H_ * W_)
#define NC_ (B_ * HW_)          // 98304 cells (~78% EMPTY: 0.25 tokens/cell)
#define NT_ (B_ * N_)           // 24576 tokens
#define EPSF 1e-6f

// Gaussian 3x3, sigma=2 (normalized): center, edge, corner
#define KW0 0.13080118f
#define KW1 0.11543166f
#define KW2 0.10186807f

// fused-kernel tiling: block = (b, 2-row pair, 32-col x-tile, 128-ch group)
#define CG_ 128                 // channels per block (lane covers 2 via float2)
#define XT_ 32                  // x columns written per block
#define XS_ 34                  // staged columns (32 + 2 halo)
#define CPB 132                 // bf16 channel pad (row = 264 B; breaks pow2 banks)
#define RY_ 2                   // output rows per block (4 staged rows, 1 per wave)
#define NWG_ (B_ * (H_ / RY_) * 3 * 2)   // 3072 blocks; 3072 % 8 == 0

// ws layout (u32 units) — round-4-proven layout (ws is actually ~384 MB).
#define OFF_ASTART 0
#define OFF_ACUR   (NC_ + 1)
#define OFF_BSUM   (2 * NC_ + 1)
#define OFF_BOFF   (2 * NC_ + 1 + 384)
#define OFF_TOKS   (2 * NC_ + 1 + 768)

__device__ __forceinline__ unsigned f2bf(float f) {   // RNE f32->bf16 (low 16)
    const unsigned u = __float_as_uint(f);
    return (u + 0x7FFFu + ((u >> 16) & 1u)) >> 16;
}

// packed 2-wide f32 FMA (VOP3P): d = a*b + c per half
__device__ __forceinline__ float2 pk_fma(float2 a, float2 b, float2 c) {
    float2 d;
    asm("v_pk_fma_f32 %0, %1, %2, %3" : "=v"(d) : "v"(a), "v"(b), "v"(c));
    return d;
}

// bf16x2 word -> float2 {even_ch, odd_ch}
__device__ __forceinline__ float2 unpk(unsigned w) {
    return make_float2(__uint_as_float(w << 16),
                       __uint_as_float(w & 0xFFFF0000u));
}

__device__ __forceinline__ void token_cell(const float* __restrict__ loc, int token,
                                           int& b, int& ix, int& iy) {
    b = token / N_;
    const float lx = fminf(fmaxf(loc[2 * token + 0], -1.0f), 1.0f);
    const float ly = fminf(fmaxf(loc[2 * token + 1], -1.0f), 1.0f);
    const float px = 0.5f * (lx + 1.0f) * (float)W_ - 0.5f;
    const float py = 0.5f * (ly + 1.0f) * (float)H_ - 0.5f;
    ix = (int)rintf(px); ix = min(max(ix, 0), W_ - 1);   // rintf = round-half-even = jnp.round
    iy = (int)rintf(py); iy = min(max(iy, 0), H_ - 1);
}

// Pass 1: histogram tokens into cells
__global__ void count_k(const float* __restrict__ loc, unsigned* __restrict__ cnts) {
    const int token = blockIdx.x * 256 + threadIdx.x;   // NT_ threads
    int b, ix, iy;
    token_cell(loc, token, b, ix, iy);
    atomicAdd(&cnts[b * HW_ + iy * W_ + ix], 1u);
}

// Pass 2a: per-block (256-cell) sums
__global__ void scanA(const unsigned* __restrict__ cnts, unsigned* __restrict__ Bsum) {
    const int i = blockIdx.x * 256 + threadIdx.x;
    int c = (int)cnts[i];
    #pragma unroll
    for (int off = 32; off > 0; off >>= 1) c += __shfl_down(c, off, 64);
    __shared__ int s[4];
    if ((threadIdx.x & 63) == 0) s[threadIdx.x >> 6] = c;
    __syncthreads();
    if (threadIdx.x == 0) Bsum[blockIdx.x] = (unsigned)(s[0] + s[1] + s[2] + s[3]);
}

// Pass 2b: exclusive scan of the 384 block sums (single block)
__global__ void scanB(const unsigned* __restrict__ Bsum, unsigned* __restrict__ Boff) {
    __shared__ unsigned s[512];
    const int t = threadIdx.x;
    const unsigned v = (t < 384) ? Bsum[t] : 0u;
    s[t] = v;
    __syncthreads();
    #pragma unroll
    for (int off = 1; off < 512; off <<= 1) {
        const unsigned a = (t >= off) ? s[t - off] : 0u;
        __syncthreads();
        s[t] += a;
        __syncthreads();
    }
    if (t < 384) Boff[t] = s[t] - v;   // exclusive
}

// Pass 2c: per-block exclusive scan + block offset -> Astart (and cursor copy)
__global__ void scanC(const unsigned* __restrict__ Boff,
                      unsigned* __restrict__ Astart, unsigned* __restrict__ Acur) {
    __shared__ unsigned s[256];
    const int t = threadIdx.x;
    const int i = blockIdx.x * 256 + t;
    const unsigned v = Acur[i];        // counts currently live in Acur
    s[t] = v;
    __syncthreads();
    #pragma unroll
    for (int off = 1; off < 256; off <<= 1) {
        const unsigned a = (t >= off) ? s[t - off] : 0u;
        __syncthreads();
        s[t] += a;
        __syncthreads();
    }
    const unsigned excl = s[t] - v + Boff[blockIdx.x];
    Astart[i] = excl;
    Acur[i]   = excl;                  // cursor starts at bin start
    if (i == 0) Astart[NC_] = NT_;     // total
}

// Pass 3: scatter token ids (packed with x) into bins
__global__ void fill_bins(const float* __restrict__ loc,
                          unsigned* __restrict__ Acur, unsigned* __restrict__ toks) {
    const int token = blockIdx.x * 256 + threadIdx.x;
    int b, ix, iy;
    token_cell(loc, token, b, ix, iy);
    const unsigned pos = atomicAdd(&Acur[b * HW_ + iy * W_ + ix], 1u);
    toks[pos] = ((unsigned)ix << 20) | (unsigned)token;
}

// Pass 4 (FUSED, 2 rows/block, branchless pk_fma fill, XCD-swizzled):
//   the round-16/19 best structure: 4 parallel gather waves (rows y0-1..y0+2),
//   bf16 LDS means, per-cell coef table, fixed-x fill threads, single
//   coalesced NCHW write, XCD-chunked block swizzle (one batch b per XCD).
__global__ __launch_bounds__(256) void fused_k(const float* __restrict__ xf,
        const unsigned* __restrict__ Astart, const unsigned* __restrict__ toks,
        float* __restrict__ out) {
    // XCD-aware swizzle: each XCD's 384-block chunk covers exactly one b.
    const int blk = (blockIdx.x & 7) * (NWG_ / 8) + (blockIdx.x >> 3);
    const int cg = blk & 1;              // ((b*64 + yp)*3 + xt)*2 + cg
    const int t2 = blk >> 1;
    const int xt = t2 % 3;
    const int t3 = t2 / 3;
    const int yp = t3 & 63;
    const int b  = t3 >> 6;
    const int y0 = yp * RY_;
    const int xs = xt * XT_;
    const int lane = threadIdx.x & 63;
    const int wv = threadIdx.x >> 6;

    __shared__ __align__(16) unsigned short means[4 * XS_ * CPB];   // 35904 B
    __shared__ unsigned long long cmask[4];
    __shared__ float coef[RY_][XT_][10];                            // 2560 B

    // (1) per-wave Astart stage for row y0-1+wv (issues early; latency
    //     overlaps the zero-init below). OOB rows -> cmask 0, empty range.
    const int yg = y0 - 1 + wv;
    const bool inrow = ((unsigned)yg < (unsigned)H_);
    unsigned p0, p1;
    {
        unsigned a = 0u;
        if (inrow && lane < XS_ + 1) {
            int g = xs - 1 + lane;                 // [xs-1, xs+33]
            g = min(max(g, 0), W_);                // Astart[..+W_] = row end
            a = Astart[b * HW_ + yg * W_ + g];
        }
        const unsigned an = __shfl_down(a, 1, 64);
        const unsigned long long mask = __ballot(lane < XS_ && an > a);
        if (lane == 0) cmask[wv] = mask;
        p0 = __shfl(a, 0, 64);
        p1 = __shfl(a, XS_, 64);
    }

    // (2) zero-init means (bf16 +0.0 = 0x0000); empty cells stay exactly 0
    {
        uint4* p4 = (uint4*)means;
        for (int i = threadIdx.x; i < 4 * XS_ * CPB / 8; i += 256)
            p4[i] = make_uint4(0u, 0u, 0u, 0u);
    }
    __syncthreads();   // A: init + cmask ready

    // (3a) wave 0: per-cell coefficient table (64 cells = 2 rows x 32 x)
    if (wv == 0) {
        const int r  = lane >> 5;
        const int xl = lane & 31;
        const int xi = xl + 1;
        const unsigned long long cm0 = cmask[r], cm1 = cmask[r + 1],
                                 cm2 = cmask[r + 2];
        const float w0 = ((cm0 >> (xi - 1)) & 1ULL) ? KW2 : 0.0f;
        const float w1 = ((cm0 >> xi)       & 1ULL) ? KW1 : 0.0f;
        const float w2 = ((cm0 >> (xi + 1)) & 1ULL) ? KW2 : 0.0f;
        const float w3 = ((cm1 >> (xi - 1)) & 1ULL) ? KW1 : 0.0f;
        const float w5 = ((cm1 >> (xi + 1)) & 1ULL) ? KW1 : 0.0f;
        const float w6 = ((cm2 >> (xi - 1)) & 1ULL) ? KW2 : 0.0f;
        const float w7 = ((cm2 >> xi)       & 1ULL) ? KW1 : 0.0f;
        const float w8 = ((cm2 >> (xi + 1)) & 1ULL) ? KW2 : 0.0f;
        const bool ne  = (cm1 >> xi) & 1ULL;
        const float ms = ((w0 + w2) + (w6 + w8)) + ((w1 + w7) + (w3 + w5));
        const float inv = ne ? 0.0f : 1.0f / (ms + EPSF);   // ms==0 -> all 0
        coef[r][xl][0] = w0 * inv;
        coef[r][xl][1] = w1 * inv;
        coef[r][xl][2] = w2 * inv;
        coef[r][xl][3] = w3 * inv;
        coef[r][xl][4] = ne ? 1.0f : 0.0f;   // self (nonempty copy)
        coef[r][xl][5] = w5 * inv;
        coef[r][xl][6] = w6 * inv;
        coef[r][xl][7] = w7 * inv;
        coef[r][xl][8] = w8 * inv;
    }

    // (3b) all waves: batch-4 contiguous CSR walk of [p0,p1) into slot wv
    if (inrow) {
        unsigned* msw = (unsigned*)(means + wv * XS_ * CPB);   // u32 view
        int cur_xi = -1;
        float acc0 = 0.0f, acc1 = 0.0f;
        unsigned cnt = 0u;
        for (unsigned p = p0; p < p1; p += 4) {
            unsigned vv[4]; float2 ff[4];
            #pragma unroll
            for (int j = 0; j < 4; ++j)
                if (p + j < p1) vv[j] = toks[p + j];
            #pragma unroll
            for (int j = 0; j < 4; ++j)
                if (p + j < p1)
                    ff[j] = *(const float2*)&xf[(size_t)(vv[j] & 0xFFFFFu) * C_
                                                + cg * CG_ + 2 * lane];
            #pragma unroll
            for (int j = 0; j < 4; ++j) {
                if (p + j >= p1) break;
                const int xi = (int)(vv[j] >> 20) - xs + 1;   // in [0, 34)
                if (xi != cur_xi) {
                    if (cur_xi >= 0) {
                        const float rcp = 1.0f / ((float)cnt + EPSF);
                        msw[cur_xi * (CPB / 2) + lane] =
                            f2bf(acc0 * rcp) | (f2bf(acc1 * rcp) << 16);
                    }
                    acc0 = acc1 = 0.0f; cnt = 0u; cur_xi = xi;
                }
                acc0 += ff[j].x; acc1 += ff[j].y; ++cnt;
            }
        }
        if (cur_xi >= 0) {
            const float rcp = 1.0f / ((float)cnt + EPSF);
            msw[cur_xi * (CPB / 2) + lane] = f2bf(acc0 * rcp) | (f2bf(acc1 * rcp) << 16);
        }
    }
    __syncthreads();   // B: means + coef ready

    // (4) fill: thread = fixed x (xl) x 16 channels x 2 rows; branchless
    //     9-term blend via uint2 LDS reads + pair-unpack + v_pk_fma_f32.
    const int xl  = threadIdx.x & 31;
    const int sub = threadIdx.x >> 5;
    const int xi  = xl + 1;
    const int c0  = sub * 16;

    #pragma unroll
    for (int r = 0; r < RY_; ++r) {
        float c9[9];
        #pragma unroll
        for (int j = 0; j < 9; ++j) c9[j] = coef[r][xl][j];

        float2 acc[8];
        #pragma unroll
        for (int p = 0; p < 8; ++p) acc[p] = make_float2(0.f, 0.f);

        #pragma unroll
        for (int j = 0; j < 9; ++j) {
            const int slot = r + j / 3;
            const int col  = xi - 1 + j % 3;
            // byte offset = (slot*XS_+col)*264 + c0*2  -> 8B-aligned (c0 mult of 16)
            const uint2* b2 = (const uint2*)(means + (slot * XS_ + col) * CPB + c0);
            const float2 wp = make_float2(c9[j], c9[j]);
            #pragma unroll
            for (int p = 0; p < 4; ++p) {
                const uint2 w = b2[p];          // channels c0+4p .. c0+4p+3
                acc[2 * p]     = pk_fma(unpk(w.x), wp, acc[2 * p]);
                acc[2 * p + 1] = pk_fma(unpk(w.y), wp, acc[2 * p + 1]);
            }
        }
        float* op = out + ((size_t)(b * C_ + cg * CG_ + c0)) * HW_
                        + (size_t)(y0 + r) * W_ + xs + xl;
        #pragma unroll
        for (int p = 0; p < 8; ++p) {
            op[(size_t)(2 * p)     * HW_] = acc[p].x;
            op[(size_t)(2 * p + 1) * HW_] = acc[p].y;
        }
    }
}

extern "C" void kernel_launch(void* const* d_in, const int* in_sizes, int n_in,
                              void* d_out, int out_size, void* d_ws, size_t ws_size,
                              hipStream_t stream) {
    const float* x   = (const float*)d_in[0];   // (B, N, C) f32
    const float* loc = (const float*)d_in[1];   // (B, N, 2) f32
    float* out = (float*)d_out;                 // (B, C, H, W) f32

    unsigned* W32 = (unsigned*)d_ws;
    unsigned* Astart = W32 + OFF_ASTART;
    unsigned* Acur   = W32 + OFF_ACUR;
    unsigned* Bsum   = W32 + OFF_BSUM;
    unsigned* Boff   = W32 + OFF_BOFF;
    unsigned* toks   = W32 + OFF_TOKS;

    hipMemsetAsync(Acur, 0, (size_t)NC_ * sizeof(unsigned), stream);

    count_k  <<<NT_ / 256, 256, 0, stream>>>(loc, Acur);
    scanA    <<<NC_ / 256, 256, 0, stream>>>(Acur, Bsum);
    scanB    <<<1, 512, 0, stream>>>(Bsum, Boff);
    scanC    <<<NC_ / 256, 256, 0, stream>>>(Boff, Astart, Acur);
    fill_bins<<<NT_ / 256, 256, 0, stream>>>(loc, Acur, toks);

    // grid = 3072 blocks (XCD-swizzled inside the kernel)
    fused_k<<<NWG_, 256, 0, stream>>>(x, Astart, toks, out);
}